// Round 7
// baseline (741.205 us; speedup 1.0000x reference)
//
#include <hip/hip_runtime.h>
#include <hip/hip_bf16.h>
#include <stdint.h>

#define BTOK 8192
#define CDIM 1024
#define NEXP 8
#define FDIM 4096
#define ECAP 1280
#define NGB (BTOK / 4)   // gate grid = 2048 blocks (4 tokens/block)

typedef __attribute__((ext_vector_type(8))) unsigned short u16x8;
typedef __attribute__((ext_vector_type(8))) __bf16 bf16x8;
typedef __attribute__((ext_vector_type(4))) float f32x4;

// counted-vmcnt pipeline primitives (T4): literal-N waitcnt + raw barrier + sched fence
#define WAIT_VM12() asm volatile("s_waitcnt vmcnt(12)" ::: "memory")
#define WAIT_VM4()  asm volatile("s_waitcnt vmcnt(4)" ::: "memory")
#define WAIT_VM0()  asm volatile("s_waitcnt vmcnt(0)" ::: "memory")
#define WAIT_LGKM0() asm volatile("s_waitcnt lgkmcnt(0)" ::: "memory")
#define SCHED_FENCE() __builtin_amdgcn_sched_barrier(0)
#define BARSCHED()  do { __builtin_amdgcn_s_barrier(); __builtin_amdgcn_sched_barrier(0); } while (0)

__device__ __forceinline__ unsigned short f2bf(float f) {
    unsigned int u = __builtin_bit_cast(unsigned int, f);
    u += 0x7FFFu + ((u >> 16) & 1u);          // round-nearest-even
    return (unsigned short)(u >> 16);
}

__device__ __forceinline__ bf16x8 lds_load8(const unsigned short* p) {
    return __builtin_bit_cast(bf16x8, *(const u16x8*)p);
}

__device__ __forceinline__ float gelu_tanh(float v) {
    // jax approximate gelu: 0.5*v*(1+tanh(0.79788456*(v+0.044715*v^3)))
    float u = 0.7978845608028654f * (v + 0.044715f * v * v * v);
    float e = __expf(2.0f * u);               // inf -> t=1, 0 -> t=-1: safe
    float t = 1.0f - 2.0f * __builtin_amdgcn_rcpf(e + 1.0f);
    return 0.5f * v * (1.0f + t);
}

// async 16B global -> LDS (wave-uniform LDS base; HW adds lane*16)
__device__ __forceinline__ void glds16(const unsigned short* g, unsigned short* l) {
    __builtin_amdgcn_global_load_lds(
        (const __attribute__((address_space(1))) void*)g,
        (__attribute__((address_space(3))) void*)l,
        16, 0, 0);
}

// A-side: stage one 128x64 bf16 K-slice into LDS (4 x global_load_lds, 16B each) [4 vmcnt]
__device__ __forceinline__ void stage_A(const unsigned short* const* gA,
                                        unsigned short* As, int wbase, int koff)
{
#pragma unroll
    for (int j = 0; j < 4; j++) glds16(gA[j] + koff, As + j * 2048 + wbase);
}

// B-side issue: 8 x float4 loads of the f32 weight K-slice into regs [8 vmcnt]
__device__ __forceinline__ void loadB(const float* const* gBf, int koff, float4* bv)
{
#pragma unroll
    for (int j = 0; j < 4; j++) {
        const float4* p = (const float4*)(gBf[j] + koff);
        bv[2 * j]     = p[0];
        bv[2 * j + 1] = p[1];
    }
}

// B-side write: convert + 4 x ds_write_b128 to the same linear slots glds would use
__device__ __forceinline__ void writeB(const float4* bv, unsigned short* Bs, int tid)
{
#pragma unroll
    for (int j = 0; j < 4; j++) {
        float4 a = bv[2 * j], b = bv[2 * j + 1];
        u16x8 o;
        o[0] = f2bf(a.x); o[1] = f2bf(a.y); o[2] = f2bf(a.z); o[3] = f2bf(a.w);
        o[4] = f2bf(b.x); o[5] = f2bf(b.y); o[6] = f2bf(b.z); o[7] = f2bf(b.w);
        *(u16x8*)(Bs + j * 2048 + tid * 8) = o;
    }
}

// 64-wide K-slice of MFMA work from given (compile-time-based) LDS buffers
__device__ __forceinline__ void mfma_tile(
    const unsigned short* As, const unsigned short* Bs,
    int wm, int wn, int fr, int kq, int sw, f32x4 acc[4][4])
{
#pragma unroll
    for (int kk = 0; kk < 64; kk += 32) {
        bf16x8 af[4], bfr[4];
#pragma unroll
        for (int i = 0; i < 4; i++) {
            af[i]  = lds_load8(&As[(wm * 64 + i * 16 + fr) * 64 + ((kk + kq) ^ sw)]);
            bfr[i] = lds_load8(&Bs[(wn * 64 + i * 16 + fr) * 64 + ((kk + kq) ^ sw)]);
        }
#pragma unroll
        for (int i = 0; i < 4; i++)
#pragma unroll
            for (int j = 0; j < 4; j++)
                acc[i][j] = __builtin_amdgcn_mfma_f32_16x16x32_bf16(af[i], bfr[j], acc[i][j], 0, 0, 0);
    }
}

// One pipeline phase: compute tile T from (CA,CB), prefetch tile T+1 into (NA,NB).
// vmcnt ledger (per wave): entry carries A(T)'s 4 glds outstanding.
//   issue B(T+1) regs (8) then A(T+1) glds (4) -> 16 outstanding
//   vmcnt(12) drains oldest 4 = A(T); barrier -> all waves' A(T)+B(T) in LDS
//   mfma; vmcnt(4) drains oldest 8 = B(T+1) regs (A(T+1) stays in flight)
//   cvt+ds_write B(T+1); lgkmcnt(0); barrier -> exit carrying A(T+1)'s 4.
__device__ __forceinline__ void ffn_phase(
    const unsigned short* const* gA, const float* const* gBf,
    const unsigned short* CA, const unsigned short* CB,
    unsigned short* NA, unsigned short* NB,
    int wbase, int tid, int koff_next, bool has_next,
    int wm, int wn, int fr, int kq, int sw, f32x4 acc[4][4])
{
    float4 bv[8];
    if (has_next) {
        loadB(gBf, koff_next, bv);
        SCHED_FENCE();
        stage_A(gA, NA, wbase, koff_next);
        SCHED_FENCE();
        WAIT_VM12();
    } else {
        WAIT_VM0();
    }
    BARSCHED();
    __builtin_amdgcn_s_setprio(1);
    mfma_tile(CA, CB, wm, wn, fr, kq, sw, acc);
    __builtin_amdgcn_s_setprio(0);
    if (has_next) {
        WAIT_VM4();
        SCHED_FENCE();
        writeB(bv, NB, tid);
        WAIT_LGKM0();
    }
    BARSCHED();
}

// ---------------- gate: logits + x->bf16 + per-token routing math + loss partials ----------------
__global__ __launch_bounds__(256) void gate_kernel(
    const float* __restrict__ x,
    const float* __restrict__ gw,
    const float* __restrict__ gb,
    unsigned short* __restrict__ xb,
    int* __restrict__ top1i, float* __restrict__ top1w,
    float* __restrict__ partials)
{
    const int lane = threadIdx.x & 63;
    const int wave = threadIdx.x >> 6;
    const int tok = blockIdx.x * 4 + wave;
    const float* xr = x + (size_t)tok * CDIM + lane * 16;
    float xv[16];
#pragma unroll
    for (int j = 0; j < 4; j++) {
        float4 v = ((const float4*)xr)[j];
        xv[4 * j] = v.x; xv[4 * j + 1] = v.y; xv[4 * j + 2] = v.z; xv[4 * j + 3] = v.w;
    }
    // fused x -> bf16
    u16x8 o0, o1;
#pragma unroll
    for (int j = 0; j < 8; j++) o0[j] = f2bf(xv[j]);
#pragma unroll
    for (int j = 0; j < 8; j++) o1[j] = f2bf(xv[8 + j]);
    unsigned short* xo = xb + (size_t)tok * CDIM + lane * 16;
    *(u16x8*)xo = o0;
    *(u16x8*)(xo + 8) = o1;

    float acc[8];
#pragma unroll
    for (int e = 0; e < 8; e++) {
        const float* wr = gw + e * CDIM + lane * 16;
        float s = 0.f;
#pragma unroll
        for (int j = 0; j < 4; j++) {
            float4 v = ((const float4*)wr)[j];
            s += xv[4 * j] * v.x + xv[4 * j + 1] * v.y + xv[4 * j + 2] * v.z + xv[4 * j + 3] * v.w;
        }
        acc[e] = s;
    }
#pragma unroll
    for (int e = 0; e < 8; e++) {
#pragma unroll
        for (int off = 32; off > 0; off >>= 1)
            acc[e] += __shfl_xor(acc[e], off);
    }
    // all lanes now hold the full logit vector; per-token math is wave-uniform
    const float INV_T = 1.0f / 1.66f;
    float l[8];
#pragma unroll
    for (int e = 0; e < 8; e++) l[e] = acc[e] + gb[e];
    float m = l[0];
#pragma unroll
    for (int e = 1; e < 8; e++) m = fmaxf(m, l[e]);
    float ex[8], se = 0.f;
#pragma unroll
    for (int e = 0; e < 8; e++) { ex[e] = __expf(l[e] - m); se += ex[e]; }
    float inv = 1.0f / se;
    int am = 0; float bl = l[0];
#pragma unroll
    for (int e = 1; e < 8; e++) if (l[e] > bl) { bl = l[e]; am = e; }  // first-max
    float w = ex[am] * inv;
    float lse = m + __logf(se);
    float zz = lse * lse;
    float m2 = m * INV_T, se2 = 0.f, ex2[8];
#pragma unroll
    for (int e = 0; e < 8; e++) { ex2[e] = __expf(l[e] * INV_T - m2); se2 += ex2[e]; }
    float inv2 = 1.0f / se2;
    float pen = 0.f, q[8];
#pragma unroll
    for (int e = 0; e < 8; e++) { q[e] = ex2[e] * inv2; pen += q[e] * (1.f - q[e]); }

    __shared__ float part[26][4];
    if (lane == 0) {
        top1i[tok] = am;
        top1w[tok] = w;
        part[0][wave] = pen;
        part[1][wave] = zz;
#pragma unroll
        for (int e = 0; e < 8; e++) {
            part[2 + e][wave]  = q[e];
            part[10 + e][wave] = ex[e] * inv;
            part[18 + e][wave] = (e == am) ? w : 0.f;
        }
    }
    __syncthreads();
    const int tid = threadIdx.x;
    if (tid < 26)
        partials[tid * NGB + blockIdx.x] =
            part[tid][0] + part[tid][1] + part[tid][2] + part[tid][3];
}

// ---------------- route: capacity scan + scatter + loss assembly (single block) ----------------
__global__ __launch_bounds__(256) void route_kernel(
    const int* __restrict__ top1i, const float* __restrict__ top1w,
    const float* __restrict__ partials,
    int* __restrict__ toks, float* __restrict__ slotw,
    int* __restrict__ cnt, float* __restrict__ aux_out)
{
    const int tid = threadIdx.x;
    const int TPT = BTOK / 256;  // 32 contiguous tokens per thread (token order!)
    int ti[TPT];
    int cnte[8] = {};
#pragma unroll
    for (int i = 0; i < TPT; i++) {
        ti[i] = top1i[tid * TPT + i];
#pragma unroll
        for (int e = 0; e < 8; e++) cnte[e] += (ti[i] == e) ? 1 : 0;
    }

    // per-expert prefix scan of per-thread counts (Hillis-Steele over 256 chunks)
    __shared__ int sc[256][8];
#pragma unroll
    for (int e = 0; e < 8; e++) sc[tid][e] = cnte[e];
    __syncthreads();
    for (int st = 1; st < 256; st <<= 1) {
        int v[8];
        bool act = (tid >= st);
        if (act) {
#pragma unroll
            for (int e = 0; e < 8; e++) v[e] = sc[tid - st][e];
        }
        __syncthreads();
        if (act) {
#pragma unroll
            for (int e = 0; e < 8; e++) sc[tid][e] += v[e];
        }
        __syncthreads();
    }
    int run[8], tot[8];
#pragma unroll
    for (int e = 0; e < 8; e++) {
        run[e] = (tid > 0) ? sc[tid - 1][e] : 0;
        tot[e] = sc[255][e];
    }
    // scatter tokens into per-expert slots (token order within each thread chunk)
#pragma unroll
    for (int i = 0; i < TPT; i++) {
        int t = tid * TPT + i;
        int am = ti[i];
        int pos = 0;
#pragma unroll
        for (int e = 0; e < 8; e++) if (e == am) pos = run[e]++;
        if (pos < ECAP) {
            toks[am * ECAP + pos] = t;
            slotw[am * ECAP + pos] = top1w[t];
        }
    }
    if (tid < 8) cnt[tid] = (tot[tid] < ECAP) ? tot[tid] : ECAP;

    // reduce the [26][NGB] gate partials (coalesced strided loads)
    float r[26];
#pragma unroll
    for (int j = 0; j < 26; j++) {
        float s = 0.f;
        for (int i = tid; i < NGB; i += 256) s += partials[j * NGB + i];
        r[j] = s;
    }
    __shared__ float red[26][256];
#pragma unroll
    for (int j = 0; j < 26; j++) red[j][tid] = r[j];
    __syncthreads();
    for (int st = 128; st > 0; st >>= 1) {
        if (tid < st) {
#pragma unroll
            for (int j = 0; j < 26; j++) red[j][tid] += red[j][tid + st];
        }
        __syncthreads();
    }
    if (tid == 0) {
        const float BTf = (float)BTOK;
        float pen_a = red[0][0] / (BTf * 8.f);
        float pb = 0.f;
        for (int e = 0; e < 8; e++) { float pm = red[2 + e][0] / BTf; pb += pm * (1.f - pm); }
        float pen_b = 0.125f - pb * 0.125f;
        float penalty = 0.01f * (pen_a + pen_b);
        float z = 0.001f * red[1][0] / BTf;
        float load = 0.f;
        for (int e = 0; e < 8; e++) load += ((float)tot[e] / BTf) * (red[10 + e][0] / BTf);
        load *= 0.01f * 8.f;
        float mu = 0.f;
        for (int e = 0; e < 8; e++) mu += red[18 + e][0];
        mu *= 0.125f;
        float var = 0.f;
        for (int e = 0; e < 8; e++) { float d = red[18 + e][0] - mu; var += d * d; }
        var *= 0.125f;
        float cv2 = var / (mu * mu);
        float aux = penalty + z + load + 0.01f * cv2;
        aux_out[0] = aux;
    }
}

// ---------------- FFN1: H = gelu(Xg @ W1^T + b1), A gathered, W1 read as f32 (fused cvt) ----------------
__global__ __launch_bounds__(256) void ffn1_kernel(
    const unsigned short* __restrict__ xb,
    const float* __restrict__ w1,
    const float* __restrict__ b1,
    const int* __restrict__ toks,
    const int* __restrict__ cnt,
    unsigned short* __restrict__ H)
{
    const int e = blockIdx.y;
    const int MT = ECAP / 128;  // 10
    // bijective XCD-aware remap: gridDim.x = 320 = 8*40
    const int nbq = (int)gridDim.x >> 3;
    const int bid = blockIdx.x;
    const int b2 = (bid & 7) * nbq + (bid >> 3);
    const int mt = b2 % MT;
    const int nt = b2 / MT;
    const int cnt_e = cnt[e];
    const int m0 = mt * 128;
    if (m0 >= cnt_e) return;
    const int n0 = nt * 128;
    const float* Wf = w1 + (size_t)e * FDIM * CDIM;
    const int* tk = toks + e * ECAP;

    __shared__ __align__(16) unsigned short As[2 * 128 * 64];
    __shared__ __align__(16) unsigned short Bs[2 * 128 * 64];

    const int tid = threadIdx.x;
    const int lane = tid & 63;
    const int wave = tid >> 6;
    const int wm = wave & 1;
    const int wn = wave >> 1;
    const int wbase = wave * 512;

    const unsigned short* gA[4];
    const float* gBf[4];
#pragma unroll
    for (int j = 0; j < 4; j++) {
        int idx = j * 256 + tid;
        int r = idx >> 3;
        int ch = (idx & 7) ^ (r & 7);     // pre-swizzled source chunk
        int row = m0 + r;
        int tokid = (row < cnt_e) ? tk[row] : 0;
        if ((unsigned)tokid >= BTOK) tokid = 0;
        gA[j] = xb + (size_t)tokid * CDIM + ch * 8;
        gBf[j] = Wf + (size_t)(n0 + r) * CDIM + ch * 8;
    }
    f32x4 acc[4][4] = {};
    const int fr = lane & 15;
    const int kq = (lane >> 4) * 8;
    const int sw = (fr & 7) << 3;

    // prologue: tile 0 -> buf0 (B via regs+cvt, A via glds)
    {
        float4 bv[8];
        loadB(gBf, 0, bv);
        SCHED_FENCE();
        stage_A(gA, As, wbase, 0);
        SCHED_FENCE();
        WAIT_VM4();      // B(0) regs landed (A(0)'s 4 glds in flight)
        writeB(bv, Bs, tid);
        WAIT_VM0();      // A(0) landed
        WAIT_LGKM0();
        BARSCHED();
    }

    const int NT = CDIM / 64;  // 16 (even)
#pragma unroll 1
    for (int t = 0; t < NT; t += 2) {
        // phase A: compute buf0 (tile t), prefetch t+1 -> buf1
        ffn_phase(gA, gBf, As, Bs, As + 8192, Bs + 8192,
                  wbase, tid, (t + 1) * 64, true,
                  wm, wn, fr, kq, sw, acc);
        // phase B: compute buf1 (tile t+1), prefetch t+2 -> buf0
        ffn_phase(gA, gBf, As + 8192, Bs + 8192, As, Bs,
                  wbase, tid, (t + 2) * 64, (t + 2 < NT),
                  wm, wn, fr, kq, sw, acc);
    }
    const int cq = (lane >> 4) * 4;
#pragma unroll
    for (int i = 0; i < 4; i++) {
#pragma unroll
        for (int j = 0; j < 4; j++) {
            int n = n0 + wn * 64 + j * 16 + fr;
            float bias = b1[e * FDIM + n];
            size_t base = ((size_t)e * ECAP + (m0 + wm * 64 + i * 16 + cq)) * FDIM + n;
#pragma unroll
            for (int rr = 0; rr < 4; rr++) {
                float v = acc[i][j][rr] + bias;
                H[base + (size_t)rr * FDIM] = f2bf(gelu_tanh(v));
            }
        }
    }
}

// ---------------- FFN2: out = w * (H @ W2^T + b2), W2 read as f32 (fused cvt) ----------------
__global__ __launch_bounds__(256) void ffn2_kernel(
    const unsigned short* __restrict__ H,
    const float* __restrict__ w2,
    const float* __restrict__ b2,
    const int* __restrict__ toks,
    const float* __restrict__ slotw,
    const int* __restrict__ cnt,
    float* __restrict__ out)
{
    const int e = blockIdx.y;
    const int MT = ECAP / 128;
    // bijective XCD-aware remap: gridDim.x = 80 = 8*10
    const int nbq = (int)gridDim.x >> 3;
    const int bid = blockIdx.x;
    const int b2i = (bid & 7) * nbq + (bid >> 3);
    const int mt = b2i % MT;
    const int nt = b2i / MT;
    const int cnt_e = cnt[e];
    const int m0 = mt * 128;
    if (m0 >= cnt_e) return;
    const int n0 = nt * 128;
    const float* Wf = w2 + (size_t)e * CDIM * FDIM;
    const unsigned short* Hb = H + (size_t)e * ECAP * FDIM;

    __shared__ __align__(16) unsigned short As[2 * 128 * 64];
    __shared__ __align__(16) unsigned short Bs[2 * 128 * 64];

    const int tid = threadIdx.x;
    const int lane = tid & 63;
    const int wave = tid >> 6;
    const int wm = wave & 1;
    const int wn = wave >> 1;
    const int wbase = wave * 512;

    const unsigned short* gA[4];
    const float* gBf[4];
#pragma unroll
    for (int j = 0; j < 4; j++) {
        int idx = j * 256 + tid;
        int r = idx >> 3;
        int ch = (idx & 7) ^ (r & 7);     // pre-swizzled source chunk
        gA[j] = Hb + (size_t)(m0 + r) * FDIM + ch * 8;
        gBf[j] = Wf + (size_t)(n0 + r) * FDIM + ch * 8;
    }
    f32x4 acc[4][4] = {};
    const int fr = lane & 15;
    const int kq = (lane >> 4) * 8;
    const int sw = (fr & 7) << 3;

    // prologue: tile 0 -> buf0
    {
        float4 bv[8];
        loadB(gBf, 0, bv);
        SCHED_FENCE();
        stage_A(gA, As, wbase, 0);
        SCHED_FENCE();
        WAIT_VM4();
        writeB(bv, Bs, tid);
        WAIT_VM0();
        WAIT_LGKM0();
        BARSCHED();
    }

    const int NT = FDIM / 64;  // 64 (even)
#pragma unroll 1
    for (int t = 0; t < NT; t += 2) {
        ffn_phase(gA, gBf, As, Bs, As + 8192, Bs + 8192,
                  wbase, tid, (t + 1) * 64, true,
                  wm, wn, fr, kq, sw, acc);
        ffn_phase(gA, gBf, As + 8192, Bs + 8192, As, Bs,
                  wbase, tid, (t + 2) * 64, (t + 2 < NT),
                  wm, wn, fr, kq, sw, acc);
    }
    const int cq = (lane >> 4) * 4;
#pragma unroll
    for (int i = 0; i < 4; i++) {
#pragma unroll
        for (int rr = 0; rr < 4; rr++) {
            int s = m0 + wm * 64 + i * 16 + cq + rr;
            if (s < cnt_e) {
                int t = toks[e * ECAP + s];
                float wgt = slotw[e * ECAP + s];
                if ((unsigned)t < BTOK) {
#pragma unroll
                    for (int j = 0; j < 4; j++) {
                        int n = n0 + wn * 64 + j * 16 + fr;
                        float y = acc[i][j][rr] + b2[e * CDIM + n];
                        out[(size_t)t * CDIM + n] = wgt * y;
                    }
                }
            }
        }
    }
}

extern "C" void kernel_launch(void* const* d_in, const int* in_sizes, int n_in,
                              void* d_out, int out_size, void* d_ws, size_t ws_size,
                              hipStream_t stream)
{
    (void)in_sizes; (void)n_in; (void)ws_size;
    const float* x  = (const float*)d_in[0];
    const float* gw = (const float*)d_in[1];
    const float* gb = (const float*)d_in[2];
    const float* w1 = (const float*)d_in[3];
    const float* b1 = (const float*)d_in[4];
    const float* w2 = (const float*)d_in[5];
    const float* b2 = (const float*)d_in[6];
    float* out = (float*)d_out;

    // workspace layout (~100 MB; weight-bf16 buffers eliminated)
    char* ws = (char*)d_ws;
    size_t off = 0;
    unsigned short* H   = (unsigned short*)(ws + off); off += (size_t)NEXP * ECAP * FDIM * 2;
    unsigned short* xb  = (unsigned short*)(ws + off); off += (size_t)BTOK * CDIM * 2;
    float* partials = (float*)(ws + off); off += (size_t)26 * NGB * 4;
    int* top1i    = (int*)(ws + off);   off += (size_t)BTOK * 4;
    float* top1w  = (float*)(ws + off); off += (size_t)BTOK * 4;
    int* toks     = (int*)(ws + off);   off += (size_t)NEXP * ECAP * 4;
    float* slotw  = (float*)(ws + off); off += (size_t)NEXP * ECAP * 4;
    int* cnt      = (int*)(ws + off);   off += (size_t)NEXP * 4;

    hipMemsetAsync(d_out, 0, (size_t)out_size * sizeof(float), stream);  // dropped tokens -> 0

    gate_kernel<<<NGB, 256, 0, stream>>>(x, gw, gb, xb, top1i, top1w, partials);
    route_kernel<<<1, 256, 0, stream>>>(top1i, top1w, partials, toks, slotw, cnt,
                                        out + (size_t)BTOK * CDIM);
    ffn1_kernel<<<dim3((ECAP / 128) * (FDIM / 128), NEXP), 256, 0, stream>>>(xb, w1, b1, toks, cnt, H);
    ffn2_kernel<<<dim3((ECAP / 128) * (CDIM / 128), NEXP), 256, 0, stream>>>(H, w2, b2, toks, slotw, cnt, out);
}

// Round 8
// 675.247 us; speedup vs baseline: 1.0977x; 1.0977x over previous
//
#include <hip/hip_runtime.h>
#include <hip/hip_bf16.h>
#include <stdint.h>

#define BTOK 8192
#define CDIM 1024
#define NEXP 8
#define FDIM 4096
#define ECAP 1280
#define NGB (BTOK / 4)   // gate grid = 2048 blocks (4 tokens/block)

typedef __attribute__((ext_vector_type(8))) unsigned short u16x8;
typedef __attribute__((ext_vector_type(8))) __bf16 bf16x8;
typedef __attribute__((ext_vector_type(4))) float f32x4;

// counted-vmcnt pipeline primitives (T4): literal-N waitcnt + raw barrier + sched fence
#define WAIT_VM4()  asm volatile("s_waitcnt vmcnt(4)" ::: "memory")
#define WAIT_VM0()  asm volatile("s_waitcnt vmcnt(0)" ::: "memory")
#define BARSCHED()  do { __builtin_amdgcn_s_barrier(); __builtin_amdgcn_sched_barrier(0); } while (0)

__device__ __forceinline__ unsigned short f2bf(float f) {
    unsigned int u = __builtin_bit_cast(unsigned int, f);
    u += 0x7FFFu + ((u >> 16) & 1u);          // round-nearest-even
    return (unsigned short)(u >> 16);
}

__device__ __forceinline__ bf16x8 lds_load8(const unsigned short* p) {
    return __builtin_bit_cast(bf16x8, *(const u16x8*)p);
}

__device__ __forceinline__ float gelu_tanh(float v) {
    // jax approximate gelu: 0.5*v*(1+tanh(0.79788456*(v+0.044715*v^3)))
    float u = 0.7978845608028654f * (v + 0.044715f * v * v * v);
    float e = __expf(2.0f * u);               // inf -> t=1, 0 -> t=-1: safe
    float t = 1.0f - 2.0f * __builtin_amdgcn_rcpf(e + 1.0f);
    return 0.5f * v * (1.0f + t);
}

// async 16B global -> LDS (wave-uniform LDS base; HW adds lane*16)
__device__ __forceinline__ void glds16(const unsigned short* g, unsigned short* l) {
    __builtin_amdgcn_global_load_lds(
        (const __attribute__((address_space(1))) void*)g,
        (__attribute__((address_space(3))) void*)l,
        16, 0, 0);
}

// stage one 128x64 A-tile + B-tile K-slice into LDS.
// 512 threads: 2 j-rounds x (1 A-glds + 1 B-glds) per wave = 4 vmcnt entries/wave/tile.
__device__ __forceinline__ void stage_tile(
    const unsigned short* const* gA, const unsigned short* const* gB,
    unsigned short* As, unsigned short* Bs, int wbase, int koff)
{
#pragma unroll
    for (int j = 0; j < 2; j++) {
        glds16(gA[j] + koff, As + j * 4096 + wbase);
        glds16(gB[j] + koff, Bs + j * 4096 + wbase);
    }
}

// 64-wide K-slice of MFMA work; per wave: 64(M) x 32(N) quadrant -> acc[4][2], 16 MFMA
__device__ __forceinline__ void mfma_tile(
    const unsigned short* As, const unsigned short* Bs,
    int wm, int wn, int fr, int kq, int sw, f32x4 acc[4][2])
{
#pragma unroll
    for (int kk = 0; kk < 64; kk += 32) {
        bf16x8 af[4], bfr[2];
#pragma unroll
        for (int i = 0; i < 4; i++)
            af[i] = lds_load8(&As[(wm * 64 + i * 16 + fr) * 64 + ((kk + kq) ^ sw)]);
#pragma unroll
        for (int j = 0; j < 2; j++)
            bfr[j] = lds_load8(&Bs[(wn * 32 + j * 16 + fr) * 64 + ((kk + kq) ^ sw)]);
#pragma unroll
        for (int i = 0; i < 4; i++)
#pragma unroll
            for (int j = 0; j < 2; j++)
                acc[i][j] = __builtin_amdgcn_mfma_f32_16x16x32_bf16(af[i], bfr[j], acc[i][j], 0, 0, 0);
    }
}

// ---------------- f32 -> packed bf16 conversion of BOTH weight tensors (one launch) ----------------
__global__ __launch_bounds__(256) void cvtw_kernel(
    const float* __restrict__ w1, const float* __restrict__ w2,
    unsigned short* __restrict__ d1, unsigned short* __restrict__ d2, int n8)
{
    const float* src = blockIdx.y ? w2 : w1;
    unsigned short* dst = blockIdx.y ? d2 : d1;
    int i = blockIdx.x * 256 + threadIdx.x;
    if (i >= n8) return;
    const float4* s = (const float4*)(src + (size_t)i * 8);
    float4 a = s[0], b = s[1];
    u16x8 o;
    o[0] = f2bf(a.x); o[1] = f2bf(a.y); o[2] = f2bf(a.z); o[3] = f2bf(a.w);
    o[4] = f2bf(b.x); o[5] = f2bf(b.y); o[6] = f2bf(b.z); o[7] = f2bf(b.w);
    *(u16x8*)(dst + (size_t)i * 8) = o;
}

// ---------------- gate: logits + x->bf16 + per-token routing math + loss partials ----------------
__global__ __launch_bounds__(256) void gate_kernel(
    const float* __restrict__ x,
    const float* __restrict__ gw,
    const float* __restrict__ gb,
    unsigned short* __restrict__ xb,
    int* __restrict__ top1i, float* __restrict__ top1w,
    float* __restrict__ partials)
{
    const int lane = threadIdx.x & 63;
    const int wave = threadIdx.x >> 6;
    const int tok = blockIdx.x * 4 + wave;
    const float* xr = x + (size_t)tok * CDIM + lane * 16;
    float xv[16];
#pragma unroll
    for (int j = 0; j < 4; j++) {
        float4 v = ((const float4*)xr)[j];
        xv[4 * j] = v.x; xv[4 * j + 1] = v.y; xv[4 * j + 2] = v.z; xv[4 * j + 3] = v.w;
    }
    // fused x -> bf16
    u16x8 o0, o1;
#pragma unroll
    for (int j = 0; j < 8; j++) o0[j] = f2bf(xv[j]);
#pragma unroll
    for (int j = 0; j < 8; j++) o1[j] = f2bf(xv[8 + j]);
    unsigned short* xo = xb + (size_t)tok * CDIM + lane * 16;
    *(u16x8*)xo = o0;
    *(u16x8*)(xo + 8) = o1;

    float acc[8];
#pragma unroll
    for (int e = 0; e < 8; e++) {
        const float* wr = gw + e * CDIM + lane * 16;
        float s = 0.f;
#pragma unroll
        for (int j = 0; j < 4; j++) {
            float4 v = ((const float4*)wr)[j];
            s += xv[4 * j] * v.x + xv[4 * j + 1] * v.y + xv[4 * j + 2] * v.z + xv[4 * j + 3] * v.w;
        }
        acc[e] = s;
    }
#pragma unroll
    for (int e = 0; e < 8; e++) {
#pragma unroll
        for (int off = 32; off > 0; off >>= 1)
            acc[e] += __shfl_xor(acc[e], off);
    }
    // all lanes now hold the full logit vector; per-token math is wave-uniform
    const float INV_T = 1.0f / 1.66f;
    float l[8];
#pragma unroll
    for (int e = 0; e < 8; e++) l[e] = acc[e] + gb[e];
    float m = l[0];
#pragma unroll
    for (int e = 1; e < 8; e++) m = fmaxf(m, l[e]);
    float ex[8], se = 0.f;
#pragma unroll
    for (int e = 0; e < 8; e++) { ex[e] = __expf(l[e] - m); se += ex[e]; }
    float inv = 1.0f / se;
    int am = 0; float bl = l[0];
#pragma unroll
    for (int e = 1; e < 8; e++) if (l[e] > bl) { bl = l[e]; am = e; }  // first-max
    float w = ex[am] * inv;
    float lse = m + __logf(se);
    float zz = lse * lse;
    float m2 = m * INV_T, se2 = 0.f, ex2[8];
#pragma unroll
    for (int e = 0; e < 8; e++) { ex2[e] = __expf(l[e] * INV_T - m2); se2 += ex2[e]; }
    float inv2 = 1.0f / se2;
    float pen = 0.f, q[8];
#pragma unroll
    for (int e = 0; e < 8; e++) { q[e] = ex2[e] * inv2; pen += q[e] * (1.f - q[e]); }

    __shared__ float part[26][4];
    if (lane == 0) {
        top1i[tok] = am;
        top1w[tok] = w;
        part[0][wave] = pen;
        part[1][wave] = zz;
#pragma unroll
        for (int e = 0; e < 8; e++) {
            part[2 + e][wave]  = q[e];
            part[10 + e][wave] = ex[e] * inv;
            part[18 + e][wave] = (e == am) ? w : 0.f;
        }
    }
    __syncthreads();
    const int tid = threadIdx.x;
    if (tid < 26)
        partials[tid * NGB + blockIdx.x] =
            part[tid][0] + part[tid][1] + part[tid][2] + part[tid][3];
}

// ---------------- route: capacity scan + scatter + loss assembly (single block) ----------------
__global__ __launch_bounds__(256) void route_kernel(
    const int* __restrict__ top1i, const float* __restrict__ top1w,
    const float* __restrict__ partials,
    int* __restrict__ toks, float* __restrict__ slotw,
    int* __restrict__ cnt, float* __restrict__ aux_out)
{
    const int tid = threadIdx.x;
    const int TPT = BTOK / 256;  // 32 contiguous tokens per thread (token order!)
    int ti[TPT];
    int cnte[8] = {};
#pragma unroll
    for (int i = 0; i < TPT; i++) {
        ti[i] = top1i[tid * TPT + i];
#pragma unroll
        for (int e = 0; e < 8; e++) cnte[e] += (ti[i] == e) ? 1 : 0;
    }

    // per-expert prefix scan of per-thread counts (Hillis-Steele over 256 chunks)
    __shared__ int sc[256][8];
#pragma unroll
    for (int e = 0; e < 8; e++) sc[tid][e] = cnte[e];
    __syncthreads();
    for (int st = 1; st < 256; st <<= 1) {
        int v[8];
        bool act = (tid >= st);
        if (act) {
#pragma unroll
            for (int e = 0; e < 8; e++) v[e] = sc[tid - st][e];
        }
        __syncthreads();
        if (act) {
#pragma unroll
            for (int e = 0; e < 8; e++) sc[tid][e] += v[e];
        }
        __syncthreads();
    }
    int run[8], tot[8];
#pragma unroll
    for (int e = 0; e < 8; e++) {
        run[e] = (tid > 0) ? sc[tid - 1][e] : 0;
        tot[e] = sc[255][e];
    }
    // scatter tokens into per-expert slots (token order within each thread chunk)
#pragma unroll
    for (int i = 0; i < TPT; i++) {
        int t = tid * TPT + i;
        int am = ti[i];
        int pos = 0;
#pragma unroll
        for (int e = 0; e < 8; e++) if (e == am) pos = run[e]++;
        if (pos < ECAP) {
            toks[am * ECAP + pos] = t;
            slotw[am * ECAP + pos] = top1w[t];
        }
    }
    if (tid < 8) cnt[tid] = (tot[tid] < ECAP) ? tot[tid] : ECAP;

    // reduce the [26][NGB] gate partials (coalesced strided loads)
    float r[26];
#pragma unroll
    for (int j = 0; j < 26; j++) {
        float s = 0.f;
        for (int i = tid; i < NGB; i += 256) s += partials[j * NGB + i];
        r[j] = s;
    }
    __shared__ float red[26][256];
#pragma unroll
    for (int j = 0; j < 26; j++) red[j][tid] = r[j];
    __syncthreads();
    for (int st = 128; st > 0; st >>= 1) {
        if (tid < st) {
#pragma unroll
            for (int j = 0; j < 26; j++) red[j][tid] += red[j][tid + st];
        }
        __syncthreads();
    }
    if (tid == 0) {
        const float BTf = (float)BTOK;
        float pen_a = red[0][0] / (BTf * 8.f);
        float pb = 0.f;
        for (int e = 0; e < 8; e++) { float pm = red[2 + e][0] / BTf; pb += pm * (1.f - pm); }
        float pen_b = 0.125f - pb * 0.125f;
        float penalty = 0.01f * (pen_a + pen_b);
        float z = 0.001f * red[1][0] / BTf;
        float load = 0.f;
        for (int e = 0; e < 8; e++) load += ((float)tot[e] / BTf) * (red[10 + e][0] / BTf);
        load *= 0.01f * 8.f;
        float mu = 0.f;
        for (int e = 0; e < 8; e++) mu += red[18 + e][0];
        mu *= 0.125f;
        float var = 0.f;
        for (int e = 0; e < 8; e++) { float d = red[18 + e][0] - mu; var += d * d; }
        var *= 0.125f;
        float cv2 = var / (mu * mu);
        float aux = penalty + z + load + 0.01f * cv2;
        aux_out[0] = aux;
    }
}

// ---------------- FFN1: H = gelu(Xg @ W1^T + b1), A gathered by token list ----------------
// 512 threads / 8 waves (2M x 4N wave grid) -> 2 waves/SIMD for intra-block TLP.
// Counted-vmcnt double-buffer (round-6 protocol, 4 loads/wave/tile):
// {stage next -> vmcnt(4) -> barrier -> mfma -> barrier}.
__global__ __launch_bounds__(512) void ffn1_kernel(
    const unsigned short* __restrict__ xb,
    const unsigned short* __restrict__ w1b,
    const float* __restrict__ b1,
    const int* __restrict__ toks,
    const int* __restrict__ cnt,
    unsigned short* __restrict__ H)
{
    const int e = blockIdx.y;
    const int MT = ECAP / 128;  // 10
    // bijective XCD-aware remap: gridDim.x = 320 = 8*40
    const int nbq = (int)gridDim.x >> 3;
    const int bid = blockIdx.x;
    const int b2 = (bid & 7) * nbq + (bid >> 3);
    const int mt = b2 % MT;
    const int nt = b2 / MT;
    const int cnt_e = cnt[e];
    const int m0 = mt * 128;
    if (m0 >= cnt_e) return;
    const int n0 = nt * 128;
    const unsigned short* W = w1b + (size_t)e * FDIM * CDIM;
    const int* tk = toks + e * ECAP;

    __shared__ __align__(16) unsigned short As[2 * 128 * 64];
    __shared__ __align__(16) unsigned short Bs[2 * 128 * 64];

    const int tid = threadIdx.x;
    const int lane = tid & 63;
    const int wave = tid >> 6;      // 0..7
    const int wm = wave & 1;        // M half
    const int wn = wave >> 1;       // N quarter (0..3)
    const int wbase = wave * 512;   // LDS elem base per wave; +j*4096 per j-round

    const unsigned short* gA[2];
    const unsigned short* gB[2];
#pragma unroll
    for (int j = 0; j < 2; j++) {
        int idx = j * 512 + tid;
        int r = idx >> 3;
        int ch = (idx & 7) ^ (r & 7);     // pre-swizzled source chunk
        int row = m0 + r;
        int tokid = (row < cnt_e) ? tk[row] : 0;  // pad rows: duplicate token 0 (discarded)
        if ((unsigned)tokid >= BTOK) tokid = 0;   // defensive
        gA[j] = xb + (size_t)tokid * CDIM + ch * 8;
        gB[j] = W + (size_t)(n0 + r) * CDIM + ch * 8;
    }
    f32x4 acc[4][2] = {};
    const int fr = lane & 15;
    const int kq = (lane >> 4) * 8;
    const int sw = (fr & 7) << 3;   // element-index XOR (bits 3..5)

    // prologue: stage tile 0 into buffer 0, full drain
    stage_tile(gA, gB, As, Bs, wbase, 0);
    WAIT_VM0();
    BARSCHED();

    const int NT = CDIM / 64;  // 16 (even)
#pragma unroll 1
    for (int t = 0; t < NT; t += 2) {
        // phase A: prefetch tile t+1 -> buf1, compute buf0 (tile t)
        stage_tile(gA, gB, As + 8192, Bs + 8192, wbase, (t + 1) * 64);
        WAIT_VM4();                 // tile t's 4 loads landed; t+1's stay in flight
        BARSCHED();
        mfma_tile(As, Bs, wm, wn, fr, kq, sw, acc);
        BARSCHED();                 // all reads of buf0 done before next overwrite
        // phase B: prefetch tile t+2 -> buf0, compute buf1 (tile t+1)
        if (t + 2 < NT) {
            stage_tile(gA, gB, As, Bs, wbase, (t + 2) * 64);
            WAIT_VM4();
        } else {
            WAIT_VM0();
        }
        BARSCHED();
        mfma_tile(As + 8192, Bs + 8192, wm, wn, fr, kq, sw, acc);
        BARSCHED();
    }
    const int cq = (lane >> 4) * 4;
#pragma unroll
    for (int i = 0; i < 4; i++) {
#pragma unroll
        for (int j = 0; j < 2; j++) {
            int n = n0 + wn * 32 + j * 16 + fr;
            float bias = b1[e * FDIM + n];
            size_t base = ((size_t)e * ECAP + (m0 + wm * 64 + i * 16 + cq)) * FDIM + n;
#pragma unroll
            for (int rr = 0; rr < 4; rr++) {
                float v = acc[i][j][rr] + bias;
                H[base + (size_t)rr * FDIM] = f2bf(gelu_tanh(v));
            }
        }
    }
}

// ---------------- FFN2: out[token] = w * (H @ W2^T + b2), scatter by slot (f32 out) ----------------
__global__ __launch_bounds__(512) void ffn2_kernel(
    const unsigned short* __restrict__ H,
    const unsigned short* __restrict__ w2b,
    const float* __restrict__ b2,
    const int* __restrict__ toks,
    const float* __restrict__ slotw,
    const int* __restrict__ cnt,
    float* __restrict__ out)
{
    const int e = blockIdx.y;
    const int MT = ECAP / 128;
    // bijective XCD-aware remap: gridDim.x = 80 = 8*10
    const int nbq = (int)gridDim.x >> 3;
    const int bid = blockIdx.x;
    const int b2i = (bid & 7) * nbq + (bid >> 3);
    const int mt = b2i % MT;
    const int nt = b2i / MT;
    const int cnt_e = cnt[e];
    const int m0 = mt * 128;
    if (m0 >= cnt_e) return;
    const int n0 = nt * 128;
    const unsigned short* W = w2b + (size_t)e * CDIM * FDIM;
    const unsigned short* Hb = H + (size_t)e * ECAP * FDIM;

    __shared__ __align__(16) unsigned short As[2 * 128 * 64];
    __shared__ __align__(16) unsigned short Bs[2 * 128 * 64];

    const int tid = threadIdx.x;
    const int lane = tid & 63;
    const int wave = tid >> 6;
    const int wm = wave & 1;
    const int wn = wave >> 1;
    const int wbase = wave * 512;

    const unsigned short* gA[2];
    const unsigned short* gB[2];
#pragma unroll
    for (int j = 0; j < 2; j++) {
        int idx = j * 512 + tid;
        int r = idx >> 3;
        int ch = (idx & 7) ^ (r & 7);     // pre-swizzled source chunk
        gA[j] = Hb + (size_t)(m0 + r) * FDIM + ch * 8;
        gB[j] = W + (size_t)(n0 + r) * FDIM + ch * 8;
    }
    f32x4 acc[4][2] = {};
    const int fr = lane & 15;
    const int kq = (lane >> 4) * 8;
    const int sw = (fr & 7) << 3;

    // prologue: stage tile 0 into buffer 0, full drain
    stage_tile(gA, gB, As, Bs, wbase, 0);
    WAIT_VM0();
    BARSCHED();

    const int NT = FDIM / 64;  // 64 (even)
#pragma unroll 1
    for (int t = 0; t < NT; t += 2) {
        stage_tile(gA, gB, As + 8192, Bs + 8192, wbase, (t + 1) * 64);
        WAIT_VM4();
        BARSCHED();
        mfma_tile(As, Bs, wm, wn, fr, kq, sw, acc);
        BARSCHED();
        if (t + 2 < NT) {
            stage_tile(gA, gB, As, Bs, wbase, (t + 2) * 64);
            WAIT_VM4();
        } else {
            WAIT_VM0();
        }
        BARSCHED();
        mfma_tile(As + 8192, Bs + 8192, wm, wn, fr, kq, sw, acc);
        BARSCHED();
    }
    const int cq = (lane >> 4) * 4;
#pragma unroll
    for (int i = 0; i < 4; i++) {
#pragma unroll
        for (int rr = 0; rr < 4; rr++) {
            int s = m0 + wm * 64 + i * 16 + cq + rr;
            if (s < cnt_e) {
                int t = toks[e * ECAP + s];
                float wgt = slotw[e * ECAP + s];
                if ((unsigned)t < BTOK) {
#pragma unroll
                    for (int j = 0; j < 2; j++) {
                        int n = n0 + wn * 32 + j * 16 + fr;
                        float y = acc[i][j][rr] + b2[e * CDIM + n];
                        out[(size_t)t * CDIM + n] = wgt * y;
                    }
                }
            }
        }
    }
}

extern "C" void kernel_launch(void* const* d_in, const int* in_sizes, int n_in,
                              void* d_out, int out_size, void* d_ws, size_t ws_size,
                              hipStream_t stream)
{
    (void)in_sizes; (void)n_in; (void)ws_size;
    const float* x  = (const float*)d_in[0];
    const float* gw = (const float*)d_in[1];
    const float* gb = (const float*)d_in[2];
    const float* w1 = (const float*)d_in[3];
    const float* b1 = (const float*)d_in[4];
    const float* w2 = (const float*)d_in[5];
    const float* b2 = (const float*)d_in[6];
    float* out = (float*)d_out;

    // workspace layout (~224.5 MB)
    char* ws = (char*)d_ws;
    size_t off = 0;
    unsigned short* H   = (unsigned short*)(ws + off); off += (size_t)NEXP * ECAP * FDIM * 2;
    unsigned short* xb  = (unsigned short*)(ws + off); off += (size_t)BTOK * CDIM * 2;
    unsigned short* w1b = (unsigned short*)(ws + off); off += (size_t)NEXP * FDIM * CDIM * 2;
    unsigned short* w2b = (unsigned short*)(ws + off); off += (size_t)NEXP * CDIM * FDIM * 2;
    float* partials = (float*)(ws + off); off += (size_t)26 * NGB * 4;
    int* top1i    = (int*)(ws + off);   off += (size_t)BTOK * 4;
    float* top1w  = (float*)(ws + off); off += (size_t)BTOK * 4;
    int* toks     = (int*)(ws + off);   off += (size_t)NEXP * ECAP * 4;
    float* slotw  = (float*)(ws + off); off += (size_t)NEXP * ECAP * 4;
    int* cnt      = (int*)(ws + off);   off += (size_t)NEXP * 4;

    hipMemsetAsync(d_out, 0, (size_t)out_size * sizeof(float), stream);  // dropped tokens -> 0

    const int NW = NEXP * FDIM * CDIM / 8;   // 4,194,304
    cvtw_kernel<<<dim3((NW + 255) / 256, 2), 256, 0, stream>>>(w1, w2, w1b, w2b, NW);

    gate_kernel<<<NGB, 256, 0, stream>>>(x, gw, gb, xb, top1i, top1w, partials);
    route_kernel<<<1, 256, 0, stream>>>(top1i, top1w, partials, toks, slotw, cnt,
                                        out + (size_t)BTOK * CDIM);
    ffn1_kernel<<<dim3((ECAP / 128) * (FDIM / 128), NEXP), 512, 0, stream>>>(xb, w1b, b1, toks, cnt, H);
    ffn2_kernel<<<dim3((ECAP / 128) * (CDIM / 128), NEXP), 512, 0, stream>>>(H, w2b, b2, toks, slotw, cnt, out);
}